// Round 13
// baseline (449.141 us; speedup 1.0000x reference)
//
#include <hip/hip_runtime.h>

#define N_TOK 2048
#define B_SZ  8
#define E_DIM 256
#define H_DIM 512
#define ITERS (N_TOK / 32)     // 64
#define QROWS 64               // q-rows per flash block
#define PT_STRIDE 40           // shorts
#define NBLK 512

typedef __attribute__((ext_vector_type(8))) short bf16x8;
typedef __attribute__((ext_vector_type(4))) float f32x4;
typedef __attribute__((ext_vector_type(4))) unsigned short u16x4;

__device__ __forceinline__ unsigned short f2bf(float f) {
    union { float f; unsigned u; } v; v.f = f;
    unsigned r = v.u + 0x7FFF + ((v.u >> 16) & 1);   // RNE
    return (unsigned short)(r >> 16);
}
__device__ __forceinline__ float bf2f(unsigned short b) {
    union { unsigned u; float f; } v; v.u = ((unsigned)b) << 16;
    return v.f;
}

// Device-scope grid barrier (graph-capture-safe; no cooperative launch).
// Release: threadfence + AGENT-scope add. Acquire: AGENT-scope acquire load
// (invalidates stale L2 per the HIP memory model) + threadfence. Timeout
// (~15ms) turns a co-residency failure into a wrong answer, not a hang.
__device__ __forceinline__ void grid_bar(int* bar) {
    __syncthreads();
    if (threadIdx.x == 0) {
        __threadfence();
        __hip_atomic_fetch_add(bar, 1, __ATOMIC_ACQ_REL, __HIP_MEMORY_SCOPE_AGENT);
        int spins = 0;
        while (__hip_atomic_load(bar, __ATOMIC_ACQUIRE,
                                 __HIP_MEMORY_SCOPE_AGENT) < NBLK) {
            __builtin_amdgcn_s_sleep(8);
            if (++spins > (1 << 16)) break;    // failsafe: no infinite hang
        }
        __threadfence();
    }
    __syncthreads();
}

// ---- ONE mega-kernel: prep | grid_bar | flash | grid_bar | scale -----------
// ROUND-13 = round-12 fusion with a capture-safe barrier (cooperative launch
// silently no-opped under graph capture: absmax == max|ref| -> out was 0).
// Theory unchanged: flash is latency-locked at ~120us (R2/R4/R5/R6/R9/R11
// falsified every in-loop wall); the target is the ~55us of inter-kernel
// overhead (R5: one extra kernel boundary cost ~+12us gap + traffic).
// 512 blocks x 256 thr, __launch_bounds__(256,2), LDS 42KB -> exactly 2
// blocks/CU co-resident (VGPR cap 256 >> ~150 used, R9 measured 84).
// Phase 1 = R7 prep math (verified), phase 2 = R9 flash body (verified,
// 120.6us), phase 3 = scale.
__launch_bounds__(256, 2)
__global__ void mega_kernel(const float* __restrict__ x,
                            const float* __restrict__ hptr,
                            unsigned short* __restrict__ Xn,
                            unsigned short* __restrict__ Vp,
                            float* __restrict__ out,
                            float* __restrict__ sumsq,
                            int* __restrict__ bars) {
    __shared__ __attribute__((aligned(16))) unsigned short Kbuf[2][32 * 256];
    __shared__ __attribute__((aligned(16))) unsigned short Pt[4][16 * PT_STRIDE];
    __shared__ float Lred[4][16];
    __shared__ __attribute__((aligned(16))) float tile[32][36];

    int bid = blockIdx.x;          // 0..511
    int t = threadIdx.x;
    int b = bid & 7;               // batch (XCD-locality heuristic only)
    int y = bid >> 3;              // 0..63
    int w = t >> 6, lane = t & 63;
    int quad = lane >> 4, nm = lane & 15;

    // ================= Phase 1a: row-normalize x -> Xn ======================
    {
        int idx = y * 4 + w;                   // 0..255
        #pragma unroll
        for (int k = 0; k < 8; k++) {
            int n = idx + 256 * k;             // 0..2047
            int r = n * 8 + b;                 // x memory order: r = n*B + b
            float4 v = *(const float4*)(x + (size_t)r * E_DIM + lane * 4);
            float s = v.x * v.x + v.y * v.y + v.z * v.z + v.w * v.w;
            #pragma unroll
            for (int o = 32; o > 0; o >>= 1) s += __shfl_xor(s, o);
            float rn = 1.0f / sqrtf(s);
            u16x4 pk;
            pk[0] = f2bf(v.x * rn); pk[1] = f2bf(v.y * rn);
            pk[2] = f2bf(v.z * rn); pk[3] = f2bf(v.w * rn);
            int u = lane >> 1, half = lane & 1;
            *(u16x4*)(Xn + ((size_t)b * N_TOK + n) * E_DIM
                         + (size_t)((u ^ (n & 7)) * 8 + half * 4)) = pk;
        }
    }

    // ================= Phase 1b: pack h -> Vp ===============================
    {
        int jb = y, j0 = jb * 32;
        for (int hb = 0; hb < 16; hb++) {
            int h0 = hb * 32;
            {
                int j = t >> 3, c = (t & 7) * 4;
                float4 v = *(const float4*)(hptr +
                    ((size_t)(j0 + j) * B_SZ + b) * H_DIM + h0 + c);
                *(float4*)(&tile[j][c]) = v;
            }
            __syncthreads();
            size_t base = ((size_t)b * (N_TOK / 32) + jb) * (H_DIM * 32);
            int hcl = t >> 3, jg = (t >> 1) & 3, half = t & 1;
            int hc = h0 + hcl;
            u16x4 pk;
            #pragma unroll
            for (int k = 0; k < 4; k++)
                pk[k] = f2bf(tile[jg * 8 + half * 4 + k][hcl]);
            *(u16x4*)(Vp + base + (size_t)(hc * 4 + (jg ^ ((hcl >> 1) & 3))) * 8
                         + half * 4) = pk;
            __syncthreads();   // tile reused next chunk
        }
    }

    grid_bar(&bars[0]);

    // ================= Phase 2: flash attention (R9 body, verbatim) =========
    {
        int qy = y & 31;               // 0..31
        int z  = bid >> 8;             // h-half
        int q0 = qy * QROWS;

        const unsigned short* Kbase = Xn + (size_t)b * N_TOK * E_DIM;
        const unsigned short* Qrow =
            Xn + ((size_t)b * N_TOK + q0 + w * 16 + nm) * E_DIM;
        const unsigned short* Vtile0 =
            Vp + (size_t)b * (N_TOK / 32) * (H_DIM * 32);
        int col0 = z * 256 + w * 64;   // this wave's PV column base

        bf16x8 qf[8];
        #pragma unroll
        for (int ec = 0; ec < 8; ec++)
            qf[ec] = *(const bf16x8*)(Qrow +
                (size_t)(((ec * 4 + quad) ^ (nm & 7)) * 8));

        f32x4 O[4][4];
        #pragma unroll
        for (int i = 0; i < 4; i++)
            #pragma unroll
            for (int j = 0; j < 4; j++) O[i][j] = (f32x4){0.f, 0.f, 0.f, 0.f};
        float l_lane[4];
        #pragma unroll
        for (int r = 0; r < 4; r++) l_lane[r] = 0.0f;

        auto stage = [&](int tile_, int buf) {
            const unsigned short* src0 = Kbase + (size_t)tile_ * 32 * E_DIM;
            #pragma unroll
            for (int k = 0; k < 4; k++) {
                int chunk = w * 4 + k;
                __builtin_amdgcn_global_load_lds(
                    (const __attribute__((address_space(1))) unsigned int*)
                        (src0 + (size_t)chunk * 512 + lane * 8),
                    (__attribute__((address_space(3))) unsigned int*)
                        (&Kbuf[buf][chunk * 512]),
                    16, 0, 0);
            }
        };

        stage(0, 0);
        int vswz = (quad ^ ((nm >> 1) & 3)) * 8;

        for (int it = 0; it < ITERS; ++it) {
            __syncthreads();
            int cur = it & 1;

            const unsigned short* Vt = Vtile0 + (size_t)it * (H_DIM * 32);
            bf16x8 vf[4];
            #pragma unroll
            for (int tt = 0; tt < 4; tt++) {
                int hc = col0 + tt * 16 + nm;
                vf[tt] = *(const bf16x8*)(Vt + (size_t)(hc * 4) * 8 + vswz);
            }

            if (it + 1 < ITERS) stage(it + 1, cur ^ 1);
            const unsigned short* KB = &Kbuf[cur][0];

            f32x4 sa = (f32x4){0.f,0.f,0.f,0.f}, sb = (f32x4){0.f,0.f,0.f,0.f};
            #pragma unroll
            for (int ec = 0; ec < 8; ec++) {
                int u = ((ec * 4 + quad) ^ (nm & 7)) * 8;
                bf16x8 kf0 = *(const bf16x8*)(KB + nm * 256 + u);
                bf16x8 kf1 = *(const bf16x8*)(KB + (16 + nm) * 256 + u);
                sa = __builtin_amdgcn_mfma_f32_16x16x32_bf16(qf[ec], kf0, sa, 0, 0, 0);
                sb = __builtin_amdgcn_mfma_f32_16x16x32_bf16(qf[ec], kf1, sb, 0, 0, 0);
            }

            #pragma unroll
            for (int r = 0; r < 4; r++) {
                unsigned short pb0 = f2bf(__expf(sa[r] - 1.0f));
                unsigned short pb1 = f2bf(__expf(sb[r] - 1.0f));
                l_lane[r] += bf2f(pb0) + bf2f(pb1);
                Pt[w][(quad * 4 + r) * PT_STRIDE + nm]      = pb0;
                Pt[w][(quad * 4 + r) * PT_STRIDE + 16 + nm] = pb1;
            }

            asm volatile("s_waitcnt lgkmcnt(0)" ::: "memory");
            __builtin_amdgcn_s_barrier();
            asm volatile("" ::: "memory");

            #pragma unroll
            for (int rg = 0; rg < 4; rg++) {
                bf16x8 pf = *(const bf16x8*)(&Pt[rg][nm * PT_STRIDE + quad * 8]);
                #pragma unroll
                for (int ct = 0; ct < 4; ct++)
                    O[rg][ct] = __builtin_amdgcn_mfma_f32_16x16x32_bf16(
                        pf, vf[ct], O[rg][ct], 0, 0, 0);
            }
        }

        // epilogue: l per row-group, normalize, write unscaled out, sumsq
        float lv[4];
        #pragma unroll
        for (int r = 0; r < 4; r++) {
            float v = l_lane[r];
            #pragma unroll
            for (int o = 1; o < 16; o <<= 1) v += __shfl_xor(v, o);
            lv[r] = v;
        }
        if (nm == 0) {
            #pragma unroll
            for (int r = 0; r < 4; r++) Lred[w][quad * 4 + r] = lv[r];
        }
        __syncthreads();

        float ss = 0.0f;
        #pragma unroll
        for (int rg = 0; rg < 4; rg++) {
            float linv[4];
            #pragma unroll
            for (int r = 0; r < 4; r++)
                linv[r] = 1.0f / Lred[rg][quad * 4 + r];
            #pragma unroll
            for (int ct = 0; ct < 4; ct++) {
                #pragma unroll
                for (int r = 0; r < 4; r++) {
                    float val = O[rg][ct][r] * linv[r];
                    int row = q0 + rg * 16 + quad * 4 + r;
                    int col = col0 + ct * 16 + nm;
                    out[((size_t)row * B_SZ + b) * H_DIM + col] = val;
                    ss += val * val;
                }
            }
        }
        #pragma unroll
        for (int o = 1; o < 64; o <<= 1) ss += __shfl_xor(ss, o);
        if (lane == 0) atomicAdd(sumsq, ss);
    }

    grid_bar(&bars[1]);

    // ================= Phase 3: global-norm rescale =========================
    {
        float rs = 1.0f / sqrtf(*sumsq);
        #pragma unroll
        for (int i = 0; i < 16; i++) {
            size_t i4 = (size_t)i * (NBLK * 256) + (size_t)bid * 256 + t;
            size_t g = i4 * 4;
            float4 v = *(float4*)(out + g);
            v.x *= rs; v.y *= rs; v.z *= rs; v.w *= rs;
            *(float4*)(out + g) = v;
        }
    }
}

extern "C" void kernel_launch(void* const* d_in, const int* in_sizes, int n_in,
                              void* d_out, int out_size, void* d_ws, size_t ws_size,
                              hipStream_t stream) {
    const float* x = (const float*)d_in[0];
    const float* h = (const float*)d_in[1];
    float* out = (float*)d_out;

    unsigned short* Xn = (unsigned short*)d_ws;                  // 8.39 MB
    unsigned short* Vp = Xn + (size_t)B_SZ * N_TOK * E_DIM;      // 16.78 MB
    float* sumsq = (float*)(Vp + (size_t)B_SZ * N_TOK * H_DIM);  // 4 B
    int* bars = (int*)(sumsq + 1);                               // 8 B

    // zero sumsq + both barrier counters (12 B) each launch — capture-safe
    hipMemsetAsync(sumsq, 0, 12, stream);
    mega_kernel<<<NBLK, 256, 0, stream>>>(x, h, Xn, Vp, out, sumsq, bars);
}

// Round 15
// 388.628 us; speedup vs baseline: 1.1557x; 1.1557x over previous
//
#include <hip/hip_runtime.h>

#define N_TOK 2048
#define B_SZ  8
#define E_DIM 256
#define H_DIM 512
#define ITERS (N_TOK / 32)     // 64
#define QROWS 64               // q-rows per flash block
#define PT_STRIDE 40           // shorts
#define FBLK 512               // flash grid size (all co-resident: 2/CU x 256)

typedef __attribute__((ext_vector_type(8))) short bf16x8;
typedef __attribute__((ext_vector_type(4))) float f32x4;
typedef __attribute__((ext_vector_type(4))) unsigned short u16x4;

__device__ __forceinline__ unsigned short f2bf(float f) {
    union { float f; unsigned u; } v; v.f = f;
    unsigned r = v.u + 0x7FFF + ((v.u >> 16) & 1);   // RNE
    return (unsigned short)(r >> 16);
}
__device__ __forceinline__ float bf2f(unsigned short b) {
    union { unsigned u; float f; } v; v.u = ((unsigned)b) << 16;
    return v.f;
}

// ---- Kernel 1: fused prep (vectorized, verified R7/R9) ---------------------
// blocks [0, 4096): row-normalize x -> Xn bf16 (B,N,E), 16B units XOR-swizzled
// blocks [4096, 12288): pack h (N,B,H) f32 -> Vp (B, N/32, H, 32) bf16, swizzled
// R13 lesson: prep KEEPS this fat grid (512-block re-grid was latency-bound).
__global__ void prep_kernel(const float* __restrict__ x,
                            const float* __restrict__ hptr,
                            unsigned short* __restrict__ Xn,
                            unsigned short* __restrict__ Vp) {
    int bid = blockIdx.x;
    int t = threadIdx.x;
    if (bid < (N_TOK * B_SZ) / 4) {
        // ---- norm path: 4 rows/block, one per wave ----
        int w = t >> 6, lane = t & 63;
        int r = bid * 4 + w;                 // row in x memory order: r = n*B + b
        int n = r >> 3, b = r & 7;
        float4 v = *(const float4*)(x + (size_t)r * E_DIM + lane * 4);
        float s = v.x * v.x + v.y * v.y + v.z * v.z + v.w * v.w;
        #pragma unroll
        for (int o = 32; o > 0; o >>= 1) s += __shfl_xor(s, o);
        float rn = 1.0f / sqrtf(s);
        u16x4 pk;
        pk[0] = f2bf(v.x * rn); pk[1] = f2bf(v.y * rn);
        pk[2] = f2bf(v.z * rn); pk[3] = f2bf(v.w * rn);
        int u = lane >> 1, half = lane & 1;
        *(u16x4*)(Xn + ((size_t)b * N_TOK + n) * E_DIM
                     + (size_t)((u ^ (n & 7)) * 8 + half * 4)) = pk;
    } else {
        // ---- pack-V path (float4 loads) ----
        int lin = bid - (N_TOK * B_SZ) / 4;    // 8192 blocks: (64, 16, 8)
        int jb = lin & 63, hb = (lin >> 6) & 15, b = lin >> 10;
        __shared__ __attribute__((aligned(16))) float tile[32][36];
        int j0 = jb * 32, h0 = hb * 32;
        {
            int j = t >> 3, c = (t & 7) * 4;
            float4 v = *(const float4*)(hptr +
                ((size_t)(j0 + j) * B_SZ + b) * H_DIM + h0 + c);
            *(float4*)(&tile[j][c]) = v;
        }
        __syncthreads();
        size_t base = ((size_t)b * (N_TOK / 32) + jb) * (H_DIM * 32);
        int hcl = t >> 3, jg = (t >> 1) & 3, half = t & 1;
        int hc = h0 + hcl;
        u16x4 pk;
        #pragma unroll
        for (int k = 0; k < 4; k++)
            pk[k] = f2bf(tile[jg * 8 + half * 4 + k][hcl]);
        *(u16x4*)(Vp + base + (size_t)(hc * 4 + (jg ^ ((hcl >> 1) & 3))) * 8
                     + half * 4) = pk;
    }
}

// Device-scope grid barrier (graph-capture-safe; mechanism VERIFIED in R13,
// where counters were reset via hipMemsetAsync — same reset used here).
// Failsafe timeout (~3.5ms) converts any co-residency surprise into a wrong
// answer instead of a container-killing hang.
__device__ __forceinline__ void grid_bar(int* bar) {
    __syncthreads();
    if (threadIdx.x == 0) {
        __threadfence();
        __hip_atomic_fetch_add(bar, 1, __ATOMIC_ACQ_REL, __HIP_MEMORY_SCOPE_AGENT);
        int spins = 0;
        while (__hip_atomic_load(bar, __ATOMIC_ACQUIRE,
                                 __HIP_MEMORY_SCOPE_AGENT) < FBLK) {
            __builtin_amdgcn_s_sleep(8);
            if (++spins > (1 << 16)) break;    // failsafe: no infinite hang
        }
        __threadfence();
    }
    __syncthreads();
}

// ---- Kernel 2: flash attention (R9 body verbatim) + fused scale phase ------
// ROUND-15 = R14 resubmit (container infra failure, like R10->R11) with the
// barrier-counter reset reverted to the R13-PROVEN hipMemsetAsync mechanism
// (R14 reset it via a plain store in prep block 0 — cross-XCD visibility of
// a plain store to another kernel's atomics is the one unproven link; gone).
// Only delta vs R13-verified code: scale fused behind the barrier, each block
// rescaling its own L2-warm 64x256 out-region. Removes one kernel boundary
// (~10-15us) + scale's HBM read. Grid (8,32,2)=512 blocks, 2/CU co-resident.
__launch_bounds__(256, 2)
__global__ void flash_kernel(const unsigned short* __restrict__ Xn,
                             const unsigned short* __restrict__ Vp,
                             float* __restrict__ out,
                             float* __restrict__ sumsq,
                             int* __restrict__ bars) {
    __shared__ __attribute__((aligned(16))) unsigned short Kbuf[2][32 * 256];
    __shared__ __attribute__((aligned(16))) unsigned short Pt[4][16 * PT_STRIDE];
    __shared__ float Lred[4][16];

    int b  = blockIdx.x;           // batch: linear-id % 8 == b -> XCD-pinned
    int q0 = blockIdx.y * QROWS;
    int z  = blockIdx.z;           // h-half
    int t = threadIdx.x;
    int w = t >> 6, lane = t & 63;
    int quad = lane >> 4, nm = lane & 15;
    // w = QK row-group AND PV col-slice (64 cols)

    const unsigned short* Kbase = Xn + (size_t)b * N_TOK * E_DIM;
    const unsigned short* Qrow =
        Xn + ((size_t)b * N_TOK + q0 + w * 16 + nm) * E_DIM;
    const unsigned short* Vtile0 = Vp + (size_t)b * (N_TOK / 32) * (H_DIM * 32);
    int col0 = z * 256 + w * 64;   // this wave's PV column base

    // Q fragments (swizzled layout: unit (ec*4+quad) ^ (row&7))
    bf16x8 qf[8];
    #pragma unroll
    for (int ec = 0; ec < 8; ec++)
        qf[ec] = *(const bf16x8*)(Qrow + (size_t)(((ec * 4 + quad) ^ (nm & 7)) * 8));

    f32x4 O[4][4];                 // [row-group][col-tile]
    #pragma unroll
    for (int i = 0; i < 4; i++)
        #pragma unroll
        for (int j = 0; j < 4; j++) O[i][j] = (f32x4){0.f, 0.f, 0.f, 0.f};
    float l_lane[4];
    #pragma unroll
    for (int r = 0; r < 4; r++) l_lane[r] = 0.0f;

    // K staging: 4 waves cooperatively copy the 16KB tile (swizzle pre-baked)
    auto stage = [&](int tile, int buf) {
        const unsigned short* src0 = Kbase + (size_t)tile * 32 * E_DIM;
        #pragma unroll
        for (int k = 0; k < 4; k++) {
            int chunk = w * 4 + k;                 // 0..15, 1KB each
            __builtin_amdgcn_global_load_lds(
                (const __attribute__((address_space(1))) unsigned int*)
                    (src0 + (size_t)chunk * 512 + lane * 8),
                (__attribute__((address_space(3))) unsigned int*)
                    (&Kbuf[buf][chunk * 512]),
                16, 0, 0);
        }
    };

    stage(0, 0);
    int vswz = (quad ^ ((nm >> 1) & 3)) * 8;

    for (int it = 0; it < ITERS; ++it) {
        __syncthreads();                 // drains staging of tile `it`
        int cur = it & 1;

        // ---- V prefetch: this wave's 64-col slice, read ONCE per block ----
        const unsigned short* Vt = Vtile0 + (size_t)it * (H_DIM * 32);
        bf16x8 vf[4];
        #pragma unroll
        for (int tt = 0; tt < 4; tt++) {
            int hc = col0 + tt * 16 + nm;
            vf[tt] = *(const bf16x8*)(Vt + (size_t)(hc * 4) * 8 + vswz);
        }

        if (it + 1 < ITERS) stage(it + 1, cur ^ 1);
        const unsigned short* KB = &Kbuf[cur][0];

        // ---- QK^T: row-group w (16 rows) x all 32 keys, K=256 ----
        f32x4 sa = (f32x4){0.f,0.f,0.f,0.f}, sb = (f32x4){0.f,0.f,0.f,0.f};
        #pragma unroll
        for (int ec = 0; ec < 8; ec++) {
            int u = ((ec * 4 + quad) ^ (nm & 7)) * 8;
            bf16x8 kf0 = *(const bf16x8*)(KB + nm * 256 + u);
            bf16x8 kf1 = *(const bf16x8*)(KB + (16 + nm) * 256 + u);
            sa = __builtin_amdgcn_mfma_f32_16x16x32_bf16(qf[ec], kf0, sa, 0, 0, 0);
            sb = __builtin_amdgcn_mfma_f32_16x16x32_bf16(qf[ec], kf1, sb, 0, 0, 0);
        }

        // ---- fixed-shift softmax: P = exp(s-1), publish both key halves ----
        #pragma unroll
        for (int r = 0; r < 4; r++) {
            unsigned short pb0 = f2bf(__expf(sa[r] - 1.0f));
            unsigned short pb1 = f2bf(__expf(sb[r] - 1.0f));
            l_lane[r] += bf2f(pb0) + bf2f(pb1);
            Pt[w][(quad * 4 + r) * PT_STRIDE + nm]      = pb0;
            Pt[w][(quad * 4 + r) * PT_STRIDE + 16 + nm] = pb1;
        }

        // raw barrier: waits DS only — staging/V loads stay in flight
        asm volatile("s_waitcnt lgkmcnt(0)" ::: "memory");
        __builtin_amdgcn_s_barrier();
        asm volatile("" ::: "memory");

        // ---- PV: all 4 row-groups x this wave's 4 col-tiles ----
        #pragma unroll
        for (int rg = 0; rg < 4; rg++) {
            bf16x8 pf = *(const bf16x8*)(&Pt[rg][nm * PT_STRIDE + quad * 8]);
            #pragma unroll
            for (int ct = 0; ct < 4; ct++)
                O[rg][ct] = __builtin_amdgcn_mfma_f32_16x16x32_bf16(
                    pf, vf[ct], O[rg][ct], 0, 0, 0);
        }
    }

    // ---- epilogue: l per row-group, normalize, write unscaled out, sumsq ---
    float lv[4];
    #pragma unroll
    for (int r = 0; r < 4; r++) {
        float v = l_lane[r];
        #pragma unroll
        for (int o = 1; o < 16; o <<= 1) v += __shfl_xor(v, o);
        lv[r] = v;
    }
    if (nm == 0) {
        #pragma unroll
        for (int r = 0; r < 4; r++) Lred[w][quad * 4 + r] = lv[r];
    }
    __syncthreads();

    float ss = 0.0f;
    #pragma unroll
    for (int rg = 0; rg < 4; rg++) {
        float linv[4];
        #pragma unroll
        for (int r = 0; r < 4; r++)
            linv[r] = 1.0f / Lred[rg][quad * 4 + r];
        #pragma unroll
        for (int ct = 0; ct < 4; ct++) {
            #pragma unroll
            for (int r = 0; r < 4; r++) {
                float val = O[rg][ct][r] * linv[r];
                int row = q0 + rg * 16 + quad * 4 + r;
                int col = col0 + ct * 16 + nm;
                out[((size_t)row * B_SZ + b) * H_DIM + col] = val;
                ss += val * val;
            }
        }
    }
    #pragma unroll
    for (int o = 1; o < 64; o <<= 1) ss += __shfl_xor(ss, o);
    if (lane == 0) atomicAdd(sumsq, ss);

    // ---- fused scale phase: grid barrier, then rescale OWN 64x256 region ---
    grid_bar(&bars[0]);
    float rs = 1.0f / sqrtf(__hip_atomic_load(sumsq, __ATOMIC_ACQUIRE,
                                              __HIP_MEMORY_SCOPE_AGENT));
    // block owns rows [q0, q0+64), cols [z*256, z*256+256) — L2-warm
    #pragma unroll
    for (int i = 0; i < 16; i++) {
        int row = q0 + i * 4 + w;
        int c4  = lane;                        // 64 float4 per row-half
        float* p = out + ((size_t)row * B_SZ + b) * H_DIM + z * 256 + c4 * 4;
        float4 v = *(float4*)p;
        v.x *= rs; v.y *= rs; v.z *= rs; v.w *= rs;
        *(float4*)p = v;
    }
}

extern "C" void kernel_launch(void* const* d_in, const int* in_sizes, int n_in,
                              void* d_out, int out_size, void* d_ws, size_t ws_size,
                              hipStream_t stream) {
    const float* x = (const float*)d_in[0];
    const float* h = (const float*)d_in[1];
    float* out = (float*)d_out;

    unsigned short* Xn = (unsigned short*)d_ws;                  // 8.39 MB
    unsigned short* Vp = Xn + (size_t)B_SZ * N_TOK * E_DIM;      // 16.78 MB
    float* sumsq = (float*)(Vp + (size_t)B_SZ * N_TOK * H_DIM);  // 4 B
    int* bars = (int*)(sumsq + 1);                               // 4 B

    // R13-proven reset mechanism: zero sumsq + barrier counter each launch
    hipMemsetAsync(sumsq, 0, 8, stream);
    prep_kernel<<<(N_TOK * B_SZ) / 4 + (N_TOK / 32) * (H_DIM / 32) * B_SZ,
                  256, 0, stream>>>(x, h, Xn, Vp);
    flash_kernel<<<dim3(B_SZ, N_TOK / QROWS, 2), 256, 0, stream>>>(
        Xn, Vp, out, sumsq, bars);
}